// Round 5
// baseline (930.303 us; speedup 1.0000x reference)
//
#include <hip/hip_runtime.h>
#include <stdint.h>

#define DEV static __device__ __forceinline__

typedef __attribute__((ext_vector_type(8))) __bf16 bf16x8;   // MFMA A/B operand
typedef __attribute__((ext_vector_type(4))) float f32x4;     // MFMA C/D operand

DEV float bfs2f(unsigned short u) {
    union { unsigned int i; float f; } c; c.i = ((unsigned int)u) << 16; return c.f;
}
DEV unsigned short f2bf(float v) {  // round-to-nearest-even f32 -> bf16 bits
    union { float f; unsigned int i; } c; c.f = v;
    return (unsigned short)((c.i + 0x7FFFu + ((c.i >> 16) & 1u)) >> 16);
}

// ---------------------------------------------------------------------------
// GEMM: C(M,N) = A(M,K) @ B(N,K)^T [+bias+softplus]
// AMODE/BMODE: 1 = operand is pre-split hi/lo bf16 planes (P0=hi, P1=lo)
//              0 = raw fp32, RNE hi/lo split on the fly
// 3 MFMA terms per 32-k block: Ah*Bh + Al*Bh + Ah*Bl (~2^-17 rel error).
// BK = 32 or 64 (1 or 2 MFMA k-blocks per stage). Register prefetch of the
// next K-tile overlaps global latency with MFMA (issued between barriers).
// LDS: per plane, per 32-k block: BM rows x 64 B (m97-verified layout).
// EPI: 0 none, 2 softplus(v+bias) clamped at 60.
// CSPLIT: epilogue routes col >= ldc to C1 (xz -> x | z split).
// grid.z = split-K; slice z covers Klen from z*Klen, writes C0 + z*pstride.
// ---------------------------------------------------------------------------
template<int BM, int BN, int BK, int AMODE, int BMODE, int EPI, int CSPLIT>
__global__ __launch_bounds__(256) void gemm_k(
    const void* __restrict__ A0, const void* __restrict__ A1,
    const void* __restrict__ B0, const void* __restrict__ B1,
    const float* __restrict__ bias,
    float* __restrict__ C0, float* __restrict__ C1,
    int lda, int ldb, int ldc, int Klen, int pstride)
{
    constexpr int FM = BM / 2 / 16;
    constexpr int FN = BN / 2 / 16;
    constexpr int KB = BK / 32;                    // 32-k sub-blocks per stage
    constexpr int GAF = (AMODE == 0) ? BM * BK / 1024 : 1;  // float4/thread
    constexpr int GAP = (AMODE == 1) ? BM * BK / 2048 : 1;  // int4-pairs/thread
    constexpr int GBF = (BMODE == 0) ? BN * BK / 1024 : 1;
    constexpr int GBP = (BMODE == 1) ? BN * BK / 2048 : 1;

    __shared__ __align__(16) char smem[2 * (BM + BN) * BK * 2];
    char* sAh = smem;
    char* sAl = smem + BM * BK * 2;
    char* sBh = smem + 2 * BM * BK * 2;
    char* sBl = smem + 2 * BM * BK * 2 + BN * BK * 2;

    const int tid = threadIdx.x, lane = tid & 63;
    const int wid = tid >> 6;
    const int wm = wid & 1, wn = wid >> 1;
    const int q = lane >> 4, t16 = lane & 15;
    const int tileM = blockIdx.x * BM, tileN = blockIdx.y * BN;
    const int kBase = blockIdx.z * Klen, kEnd = kBase + Klen;
    float* C = C0 + (size_t)blockIdx.z * pstride;

    f32x4 acc[FM][FN];
#pragma unroll
    for (int a = 0; a < FM; ++a)
#pragma unroll
        for (int b = 0; b < FN; ++b) acc[a][b] = f32x4{0.f, 0.f, 0.f, 0.f};

    float4 aF[GAF], bF[GBF];
    int4 aH[GAP], aL[GAP], bH[GBP], bL[GBP];

    auto loadA = [&](int k0) {
        if (AMODE == 0) {
            const float* A32 = (const float*)A0;
#pragma unroll
            for (int u = 0; u < GAF; ++u) {
                int idx = u * 256 + tid;
                int r = idx / (BK / 4), c4 = idx % (BK / 4);
                aF[u] = *(const float4*)(A32 + (size_t)(tileM + r) * lda + k0 + c4 * 4);
            }
        } else {
            const unsigned short* Ah = (const unsigned short*)A0;
            const unsigned short* Al = (const unsigned short*)A1;
#pragma unroll
            for (int u = 0; u < GAP; ++u) {
                int idx = u * 256 + tid;
                int r = idx / (BK / 8), c8 = idx % (BK / 8);
                size_t src = (size_t)(tileM + r) * lda + k0 + c8 * 8;
                aH[u] = *(const int4*)(Ah + src);
                aL[u] = *(const int4*)(Al + src);
            }
        }
    };
    auto loadB = [&](int k0) {
        if (BMODE == 0) {
            const float* B32 = (const float*)B0;
#pragma unroll
            for (int u = 0; u < GBF; ++u) {
                int idx = u * 256 + tid;
                int r = idx / (BK / 4), c4 = idx % (BK / 4);
                bF[u] = *(const float4*)(B32 + (size_t)(tileN + r) * ldb + k0 + c4 * 4);
            }
        } else {
            const unsigned short* Bh = (const unsigned short*)B0;
            const unsigned short* Bl = (const unsigned short*)B1;
#pragma unroll
            for (int u = 0; u < GBP; ++u) {
                int idx = u * 256 + tid;
                int r = idx / (BK / 8), c8 = idx % (BK / 8);
                size_t src = (size_t)(tileN + r) * ldb + k0 + c8 * 8;
                bH[u] = *(const int4*)(Bh + src);
                bL[u] = *(const int4*)(Bl + src);
            }
        }
    };
    auto storeA = [&]() {
        if (AMODE == 0) {
#pragma unroll
            for (int u = 0; u < GAF; ++u) {
                int idx = u * 256 + tid;
                int r = idx / (BK / 4), c4 = idx % (BK / 4);
                float vv[4] = {aF[u].x, aF[u].y, aF[u].z, aF[u].w};
                ushort4 hv, lv;
                unsigned short* hp = (unsigned short*)&hv;
                unsigned short* lp = (unsigned short*)&lv;
#pragma unroll
                for (int e = 0; e < 4; ++e) {
                    unsigned short hb = f2bf(vv[e]);
                    hp[e] = hb; lp[e] = f2bf(vv[e] - bfs2f(hb));
                }
                int off = (c4 / 8) * BM * 64 + r * 64 + (c4 & 7) * 8;
                *(ushort4*)(sAh + off) = hv;
                *(ushort4*)(sAl + off) = lv;
            }
        } else {
#pragma unroll
            for (int u = 0; u < GAP; ++u) {
                int idx = u * 256 + tid;
                int r = idx / (BK / 8), c8 = idx % (BK / 8);
                int off = (c8 / 4) * BM * 64 + r * 64 + (c8 & 3) * 16;
                *(int4*)(sAh + off) = aH[u];
                *(int4*)(sAl + off) = aL[u];
            }
        }
    };
    auto storeB = [&]() {
        if (BMODE == 0) {
#pragma unroll
            for (int u = 0; u < GBF; ++u) {
                int idx = u * 256 + tid;
                int r = idx / (BK / 4), c4 = idx % (BK / 4);
                float vv[4] = {bF[u].x, bF[u].y, bF[u].z, bF[u].w};
                ushort4 hv, lv;
                unsigned short* hp = (unsigned short*)&hv;
                unsigned short* lp = (unsigned short*)&lv;
#pragma unroll
                for (int e = 0; e < 4; ++e) {
                    unsigned short hb = f2bf(vv[e]);
                    hp[e] = hb; lp[e] = f2bf(vv[e] - bfs2f(hb));
                }
                int off = (c4 / 8) * BN * 64 + r * 64 + (c4 & 7) * 8;
                *(ushort4*)(sBh + off) = hv;
                *(ushort4*)(sBl + off) = lv;
            }
        } else {
#pragma unroll
            for (int u = 0; u < GBP; ++u) {
                int idx = u * 256 + tid;
                int r = idx / (BK / 8), c8 = idx % (BK / 8);
                int off = (c8 / 4) * BN * 64 + r * 64 + (c8 & 3) * 16;
                *(int4*)(sBh + off) = bH[u];
                *(int4*)(sBl + off) = bL[u];
            }
        }
    };

    loadA(kBase); loadB(kBase);
    for (int k0 = kBase; k0 < kEnd; k0 += BK) {
        storeA(); storeB();
        __syncthreads();
        if (k0 + BK < kEnd) { loadA(k0 + BK); loadB(k0 + BK); }  // prefetch
#pragma unroll
        for (int kb = 0; kb < KB; ++kb) {
            bf16x8 ah[FM], al[FM], bh[FN], bl[FN];
#pragma unroll
            for (int fm = 0; fm < FM; ++fm) {
                int off = kb * BM * 64 + (wm * (BM / 2) + fm * 16 + t16) * 64 + q * 16;
                ah[fm] = *(const bf16x8*)(sAh + off);
                al[fm] = *(const bf16x8*)(sAl + off);
            }
#pragma unroll
            for (int fn = 0; fn < FN; ++fn) {
                int off = kb * BN * 64 + (wn * (BN / 2) + fn * 16 + t16) * 64 + q * 16;
                bh[fn] = *(const bf16x8*)(sBh + off);
                bl[fn] = *(const bf16x8*)(sBl + off);
            }
#pragma unroll
            for (int fm = 0; fm < FM; ++fm)
#pragma unroll
                for (int fn = 0; fn < FN; ++fn) {
                    acc[fm][fn] = __builtin_amdgcn_mfma_f32_16x16x32_bf16(ah[fm], bh[fn], acc[fm][fn], 0, 0, 0);
                    acc[fm][fn] = __builtin_amdgcn_mfma_f32_16x16x32_bf16(al[fm], bh[fn], acc[fm][fn], 0, 0, 0);
                    acc[fm][fn] = __builtin_amdgcn_mfma_f32_16x16x32_bf16(ah[fm], bl[fn], acc[fm][fn], 0, 0, 0);
                }
        }
        __syncthreads();
    }

    // ---- epilogue: C/D layout col=lane&15, row=(lane>>4)*4+reg  (m89/m91)
#pragma unroll
    for (int fm = 0; fm < FM; ++fm) {
        int row0 = tileM + wm * (BM / 2) + fm * 16 + q * 4;
#pragma unroll
        for (int fn = 0; fn < FN; ++fn) {
            int col = tileN + wn * (BN / 2) + fn * 16 + t16;
            float* Cd = C; int cc2 = col;
            if (CSPLIT && col >= ldc) { Cd = C1; cc2 = col - ldc; }
            float bv = (EPI == 2) ? bias[col] : 0.f;
#pragma unroll
            for (int r = 0; r < 4; ++r) {
                float v = acc[fm][fn][r];
                if (EPI == 2) { v = fminf(v + bv, 60.f); v = log1pf(__expf(v)); }
                Cd[(size_t)(row0 + r) * ldc + cc2] = v;
            }
        }
    }
}

// ---------------------------------------------------------------------------
// reduce split-K partials (+bias) -> hi/lo planes (+ optional last-row fp32)
__global__ __launch_bounds__(256) void reduce_k(
    const float* __restrict__ part, int Z, int pstride, int n,
    const float* __restrict__ bias, int colmask,
    unsigned short* __restrict__ hi, unsigned short* __restrict__ lo,
    float* __restrict__ hlast, int colbits)
{
    int i = blockIdx.x * 256 + threadIdx.x;
    if (i >= n) return;
    float s = 0.f;
    for (int z = 0; z < Z; ++z) s += part[(size_t)z * pstride + i];
    if (bias) s += bias[i & colmask];
    unsigned short hb = f2bf(s);
    hi[i] = hb; lo[i] = f2bf(s - bfs2f(hb));
    if (hlast) {
        int row = i >> colbits;
        if ((row & 255) == 255)
            hlast[((row >> 8) << colbits) + (i & colmask)] = s;
    }
}

// causal depthwise conv (DC=4) + SiLU: xbuf(1024x1024) -> xc planes
__global__ __launch_bounds__(256) void conv_silu_k(
    const float* __restrict__ xb, const float* __restrict__ cw,
    const float* __restrict__ cb, unsigned short* __restrict__ xch,
    unsigned short* __restrict__ xcl)
{
    int i  = blockIdx.x * 256 + threadIdx.x;  // (bl, d)
    int d  = i & 1023;
    int bl = i >> 10;
    int l  = bl & 255;
    float a = cb[d];
#pragma unroll
    for (int k = 0; k < 4; ++k) {
        int ls = l + k - 3;
        if (ls >= 0) a += xb[(size_t)(bl + k - 3) * 1024 + d] * cw[d * 4 + k];
    }
    float v = a / (1.f + __expf(-a));
    unsigned short hb = f2bf(v);
    xch[i] = hb; xcl[i] = f2bf(v - bfs2f(hb));
}

// ---------------------------------------------------------------------------
// selective scan fused with +xc*D and *silu(z); 8 threads/channel (2 states ea)
// grid: 128 blocks = 4 batches x 32 chunks of 32 channels.
__global__ __launch_bounds__(256) void scan_k(
    const float* __restrict__ zb,
    const unsigned short* __restrict__ xch, const unsigned short* __restrict__ xcl,
    const unsigned short* __restrict__ xdh, const unsigned short* __restrict__ xdl,
    const float* __restrict__ dt, const float* __restrict__ Alog,
    const float* __restrict__ Dp,
    unsigned short* __restrict__ ygh, unsigned short* __restrict__ ygl)
{
    __shared__ float BC[2048];                // 64 l x 32 (Bm|Cm)
    int b    = blockIdx.x >> 5;
    int d    = ((blockIdx.x & 31) << 5) + (threadIdx.x >> 3);
    int sub  = threadIdx.x & 7;
    int j0   = sub * 2;
    float An[2], hst[2] = {0.f, 0.f};
#pragma unroll
    for (int j = 0; j < 2; ++j) An[j] = -__expf(Alog[d * 16 + j0 + j]);
    float Dd  = Dp[d];
    int   bl0 = b * 256;
    float dtv = dt[(size_t)bl0 * 1024 + d];
    float xcv = bfs2f(xch[(size_t)bl0 * 1024 + d]) + bfs2f(xcl[(size_t)bl0 * 1024 + d]);
    float zv  = zb[(size_t)bl0 * 1024 + d];

    for (int c = 0; c < 4; ++c) {
        __syncthreads();
#pragma unroll
        for (int it = 0; it < 8; ++it) {
            int j2 = it * 256 + threadIdx.x;
            size_t src = (size_t)(bl0 + c * 64 + (j2 >> 5)) * 64 + 32 + (j2 & 31);
            BC[j2] = bfs2f(xdh[src]) + bfs2f(xdl[src]);
        }
        __syncthreads();
        for (int li = 0; li < 64; ++li) {
            int l   = c * 64 + li;
            int bln = bl0 + (l + 1 < 256 ? l + 1 : 255);   // depth-1 prefetch
            float dtn = dt[(size_t)bln * 1024 + d];
            float xcn = bfs2f(xch[(size_t)bln * 1024 + d]) + bfs2f(xcl[(size_t)bln * 1024 + d]);
            float zn  = zb[(size_t)bln * 1024 + d];

            float c1 = dtv * xcv;
            const float* Bm = &BC[li * 32 + j0];
            const float* Cm = &BC[li * 32 + 16 + j0];
            float y = 0.f;
#pragma unroll
            for (int j = 0; j < 2; ++j) {
                float dA = __expf(dtv * An[j]);
                hst[j] = dA * hst[j] + c1 * Bm[j];
                y += hst[j] * Cm[j];
            }
            y += __shfl_xor(y, 1);
            y += __shfl_xor(y, 2);
            y += __shfl_xor(y, 4);
            if (sub == 0) {
                float sz = zv / (1.f + __expf(-zv));
                float v  = (y + xcv * Dd) * sz;
                unsigned short hb = f2bf(v);
                size_t o = (size_t)(bl0 + l) * 1024 + d;
                ygh[o] = hb; ygl[o] = f2bf(v - bfs2f(hb));
            }
            dtv = dtn; xcv = xcn; zv = zn;
        }
    }
}

// ---------------------------------------------------------------------------
// LayerNorm of hlast (4 x 512) -> hn
__global__ __launch_bounds__(512) void ln_k(
    const float* __restrict__ hlast, const float* __restrict__ g,
    const float* __restrict__ bb, float* __restrict__ hn)
{
    __shared__ float red[16];
    int b = blockIdx.x, k = threadIdx.x;
    float x = hlast[b * 512 + k];
    float s = x, s2 = x * x;
#pragma unroll
    for (int m = 32; m; m >>= 1) { s += __shfl_xor(s, m, 64); s2 += __shfl_xor(s2, m, 64); }
    if ((k & 63) == 0) { red[k >> 6] = s; red[8 + (k >> 6)] = s2; }
    __syncthreads();
    float ts = 0.f, ts2 = 0.f;
#pragma unroll
    for (int j = 0; j < 8; ++j) { ts += red[j]; ts2 += red[8 + j]; }
    float mu   = ts * (1.f / 512.f);
    float var  = ts2 * (1.f / 512.f) - mu * mu;
    float rstd = rsqrtf(var + 1e-5f);
    hn[b * 512 + k] = (x - mu) * rstd * g[k] + bb[k];
}

// final: out(4,16384) = hn(4,512) @ out_w(16384,512)^T + out_b  (fp32)
__global__ __launch_bounds__(256) void final_k(
    const float* __restrict__ hn, const float* __restrict__ W,
    const float* __restrict__ ob, float* __restrict__ out)
{
    int wid = threadIdx.x >> 6, lane = threadIdx.x & 63;
    float a[4][8];
#pragma unroll
    for (int b2 = 0; b2 < 4; ++b2) {
        float4 v0 = *(const float4*)&hn[b2 * 512 + lane * 8];
        float4 v1 = *(const float4*)&hn[b2 * 512 + lane * 8 + 4];
        a[b2][0] = v0.x; a[b2][1] = v0.y; a[b2][2] = v0.z; a[b2][3] = v0.w;
        a[b2][4] = v1.x; a[b2][5] = v1.y; a[b2][6] = v1.z; a[b2][7] = v1.w;
    }
#pragma unroll 1
    for (int it = 0; it < 8; ++it) {
        int n = blockIdx.x * 4 + wid + it * 2048;
        const float* W32 = W + (size_t)n * 512 + lane * 8;
        float4 v0 = *(const float4*)W32;
        float4 v1 = *(const float4*)(W32 + 4);
        float wf[8] = {v0.x, v0.y, v0.z, v0.w, v1.x, v1.y, v1.z, v1.w};
        float s0 = 0.f, s1 = 0.f, s2 = 0.f, s3 = 0.f;
#pragma unroll
        for (int j = 0; j < 8; ++j) {
            s0 += a[0][j] * wf[j]; s1 += a[1][j] * wf[j];
            s2 += a[2][j] * wf[j]; s3 += a[3][j] * wf[j];
        }
#pragma unroll
        for (int m = 32; m; m >>= 1) {
            s0 += __shfl_xor(s0, m, 64); s1 += __shfl_xor(s1, m, 64);
            s2 += __shfl_xor(s2, m, 64); s3 += __shfl_xor(s3, m, 64);
        }
        if (lane == 0) {
            float bv = ob[n];
            out[0 * 16384 + n] = s0 + bv;
            out[1 * 16384 + n] = s1 + bv;
            out[2 * 16384 + n] = s2 + bv;
            out[3 * 16384 + n] = s3 + bv;
        }
    }
}

// ---------------------------------------------------------------------------
extern "C" void kernel_launch(void* const* d_in, const int* in_sizes, int n_in,
                              void* d_out, int out_size, void* d_ws, size_t ws_size,
                              hipStream_t stream)
{
    const float* x      = (const float*)d_in[0];
    const float* in_w   = (const float*)d_in[1];
    const float* in_b   = (const float*)d_in[2];
    const float* ln_g   = (const float*)d_in[3];
    const float* ln_b   = (const float*)d_in[4];
    const float* out_w  = (const float*)d_in[5];
    const float* out_b  = (const float*)d_in[6];
    const float* m_in_w = (const float*)d_in[7];
    const float* conv_w = (const float*)d_in[8];
    const float* conv_b = (const float*)d_in[9];
    const float* xproj_w= (const float*)d_in[10];
    const float* dt_w   = (const float*)d_in[11];
    const float* dt_b   = (const float*)d_in[12];
    const float* A_log  = (const float*)d_in[13];
    const float* D_p    = (const float*)d_in[14];
    const float* m_out_w= (const float*)d_in[15];

    // ---- ws layout, peak 18.4 MB (< proven-safe 23.3 MB) ----
    char* W = (char*)d_ws;
    unsigned short* hplh = (unsigned short*)(W + 0);          // h hi  1 MB
    unsigned short* hpll = (unsigned short*)(W + 1048576);    // h lo  1 MB
    float* hlast = (float*)(W + 2097152);                     // 8 KB
    float* hn    = (float*)(W + 2162688);                     // 8 KB
    float* xbuf  = (float*)(W + 2228224);                     // 4 MB
    float* zbuf  = (float*)(W + 6422528);                     // 4 MB
    unsigned short* xch = (unsigned short*)(W + 10616832);    // 2 MB
    unsigned short* xcl = (unsigned short*)(W + 12713984);    // 2 MB
    float* dtb   = (float*)(W + 14811136);                    // 4 MB
    unsigned short* xdbh  = (unsigned short*)(W + 19005440);  // 128 KB
    unsigned short* xdbl_ = (unsigned short*)(W + 19136512);  // 128 KB
    // aliases (sequencing-safe):
    float* part1 = (float*)(W + 2228224);                     // 16 MB, pre-layer only
    float* partx = (float*)(W + 14811136);                    // 2 MB, dead before dtb written
    float* parto = (float*)(W + 6422528);                     // 8 MB over zbuf+xc (dead post-scan)
    unsigned short* ygh = (unsigned short*)(W + 2228224);     // 2 MB over xbuf (dead post-conv)
    unsigned short* ygl = (unsigned short*)(W + 4325376);     // 2 MB

    // h = x @ in_w.T + in_b   (split-K=8, 512 blocks)
    gemm_k<128,64,64,0,0,0,0><<<dim3(8,8,8),256,0,stream>>>(
        x, nullptr, in_w, nullptr, nullptr, part1, nullptr,
        16384, 16384, 512, 2048, 524288);
    reduce_k<<<2048,256,0,stream>>>(part1, 8, 524288, 524288, in_b, 511,
                                    hplh, hpll, hlast, 9);

    for (int i = 0; i < 4; ++i) {
        const float* iw = m_in_w  + (size_t)i * 1048576;
        const float* cw = conv_w  + (size_t)i * 4096;
        const float* cb = conv_b  + (size_t)i * 1024;
        const float* xw = xproj_w + (size_t)i * 65536;
        const float* dw = dt_w    + (size_t)i * 32768;
        const float* db = dt_b    + (size_t)i * 1024;
        const float* Al = A_log   + (size_t)i * 16384;
        const float* Dp = D_p     + (size_t)i * 1024;
        const float* ow = m_out_w + (size_t)i * 524288;

        // xz = h @ iw.T  (1024x2048, K=512) -> xbuf | zbuf  (256 blocks)
        gemm_k<64,128,64,1,0,0,1><<<dim3(16,16,1),256,0,stream>>>(
            hplh, hpll, iw, nullptr, nullptr, xbuf, zbuf, 512, 512, 1024, 512, 0);
        // xc = silu(causal_conv(xbuf)) -> planes
        conv_silu_k<<<4096,256,0,stream>>>(xbuf, cw, cb, xch, xcl);
        // xdbl = xc @ xw.T  (1024x64, K=1024, split-K=8 -> 128 blocks)
        gemm_k<64,64,64,1,0,0,0><<<dim3(16,1,8),256,0,stream>>>(
            xch, xcl, xw, nullptr, nullptr, partx, nullptr, 1024, 1024, 64, 128, 65536);
        reduce_k<<<256,256,0,stream>>>(partx, 8, 65536, 65536, nullptr, 63,
                                       xdbh, xdbl_, nullptr, 6);
        // dt = softplus(xdbl[:, :32] @ dw.T + db)  (1024x1024, K=32, 256 blocks)
        gemm_k<64,64,32,1,0,2,0><<<dim3(16,16,1),256,0,stream>>>(
            xdbh, xdbl_, dw, nullptr, db, dtb, nullptr, 64, 32, 1024, 32, 0);
        // yg = (scan + xc*D) * silu(z) -> planes (128 blocks)
        scan_k<<<128,256,0,stream>>>(zbuf, xch, xcl, xdbh, xdbl_, dtb, Al, Dp,
                                     ygh, ygl);
        // h = yg @ ow.T  (1024x512, K=1024, split-K=4 -> 256 blocks)
        gemm_k<64,128,64,1,0,0,0><<<dim3(16,4,4),256,0,stream>>>(
            ygh, ygl, ow, nullptr, nullptr, parto, nullptr, 1024, 1024, 512, 256, 524288);
        reduce_k<<<2048,256,0,stream>>>(parto, 4, 524288, 524288, nullptr, 511,
                                        hplh, hpll, hlast, 9);
    }

    ln_k<<<4,512,0,stream>>>(hlast, ln_g, ln_b, hn);
    final_k<<<512,256,0,stream>>>(hn, out_w, out_b, (float*)d_out);
}

// Round 6
// 838.582 us; speedup vs baseline: 1.1094x; 1.1094x over previous
//
#include <hip/hip_runtime.h>
#include <stdint.h>

#define DEV static __device__ __forceinline__

typedef __attribute__((ext_vector_type(8))) __bf16 bf16x8;   // MFMA A/B operand
typedef __attribute__((ext_vector_type(4))) float f32x4;     // MFMA C/D operand

DEV float bfs2f(unsigned short u) {
    union { unsigned int i; float f; } c; c.i = ((unsigned int)u) << 16; return c.f;
}
DEV unsigned short f2bf(float v) {  // round-to-nearest-even f32 -> bf16 bits
    union { float f; unsigned int i; } c; c.f = v;
    return (unsigned short)((c.i + 0x7FFFu + ((c.i >> 16) & 1u)) >> 16);
}

// ---------------------------------------------------------------------------
// GEMM: C(M,N) = A(M,K) @ B(N,K)^T [+bias+softplus]
// AMODE/BMODE: 1 = operand is pre-split hi/lo bf16 planes (P0=hi, P1=lo)
//              0 = raw fp32, RNE hi/lo split on the fly
// 3 MFMA terms per 32-k block: Ah*Bh + Al*Bh + Ah*Bl (~2^-17 rel error).
// BK = 32 or 64. Register prefetch of next K-tile overlaps global latency.
// LDS per plane per 32-k block: rows x 64 B (m97-verified layout).
// EPI: 0 none, 2 softplus(v+bias) clamped at 60.
// CSPLIT: epilogue routes col >= ldc to C1 (xz -> x | z split).
// grid.z = split-K; slice z covers Klen from z*Klen, writes C0 + z*pstride.
// ---------------------------------------------------------------------------
template<int BM, int BN, int BK, int AMODE, int BMODE, int EPI, int CSPLIT>
__global__ __launch_bounds__(256) void gemm_k(
    const void* __restrict__ A0, const void* __restrict__ A1,
    const void* __restrict__ B0, const void* __restrict__ B1,
    const float* __restrict__ bias,
    float* __restrict__ C0, float* __restrict__ C1,
    int lda, int ldb, int ldc, int Klen, int pstride)
{
    constexpr int FM = BM / 2 / 16;
    constexpr int FN = BN / 2 / 16;
    constexpr int KB = BK / 32;                    // 32-k sub-blocks per stage
    constexpr int GAF = (AMODE == 0) ? BM * BK / 1024 : 1;  // float4/thread
    constexpr int GAP = (AMODE == 1) ? BM * BK / 2048 : 1;  // int4-pairs/thread
    constexpr int GBF = (BMODE == 0) ? BN * BK / 1024 : 1;
    constexpr int GBP = (BMODE == 1) ? BN * BK / 2048 : 1;

    __shared__ __align__(16) char smem[2 * (BM + BN) * BK * 2];
    char* sAh = smem;
    char* sAl = smem + BM * BK * 2;
    char* sBh = smem + 2 * BM * BK * 2;
    char* sBl = smem + 2 * BM * BK * 2 + BN * BK * 2;

    const int tid = threadIdx.x, lane = tid & 63;
    const int wid = tid >> 6;
    const int wm = wid & 1, wn = wid >> 1;
    const int q = lane >> 4, t16 = lane & 15;
    const int tileM = blockIdx.x * BM, tileN = blockIdx.y * BN;
    const int kBase = blockIdx.z * Klen, kEnd = kBase + Klen;
    float* C = C0 + (size_t)blockIdx.z * pstride;

    f32x4 acc[FM][FN];
#pragma unroll
    for (int a = 0; a < FM; ++a)
#pragma unroll
        for (int b = 0; b < FN; ++b) acc[a][b] = f32x4{0.f, 0.f, 0.f, 0.f};

    float4 aF[GAF], bF[GBF];
    int4 aH[GAP], aL[GAP], bH[GBP], bL[GBP];

    auto loadA = [&](int k0) {
        if (AMODE == 0) {
            const float* A32 = (const float*)A0;
#pragma unroll
            for (int u = 0; u < GAF; ++u) {
                int idx = u * 256 + tid;
                int r = idx / (BK / 4), c4 = idx % (BK / 4);
                aF[u] = *(const float4*)(A32 + (size_t)(tileM + r) * lda + k0 + c4 * 4);
            }
        } else {
            const unsigned short* Ah = (const unsigned short*)A0;
            const unsigned short* Al = (const unsigned short*)A1;
#pragma unroll
            for (int u = 0; u < GAP; ++u) {
                int idx = u * 256 + tid;
                int r = idx / (BK / 8), c8 = idx % (BK / 8);
                size_t src = (size_t)(tileM + r) * lda + k0 + c8 * 8;
                aH[u] = *(const int4*)(Ah + src);
                aL[u] = *(const int4*)(Al + src);
            }
        }
    };
    auto loadB = [&](int k0) {
        if (BMODE == 0) {
            const float* B32 = (const float*)B0;
#pragma unroll
            for (int u = 0; u < GBF; ++u) {
                int idx = u * 256 + tid;
                int r = idx / (BK / 4), c4 = idx % (BK / 4);
                bF[u] = *(const float4*)(B32 + (size_t)(tileN + r) * ldb + k0 + c4 * 4);
            }
        } else {
            const unsigned short* Bh = (const unsigned short*)B0;
            const unsigned short* Bl = (const unsigned short*)B1;
#pragma unroll
            for (int u = 0; u < GBP; ++u) {
                int idx = u * 256 + tid;
                int r = idx / (BK / 8), c8 = idx % (BK / 8);
                size_t src = (size_t)(tileN + r) * ldb + k0 + c8 * 8;
                bH[u] = *(const int4*)(Bh + src);
                bL[u] = *(const int4*)(Bl + src);
            }
        }
    };
    auto storeA = [&]() {
        if (AMODE == 0) {
#pragma unroll
            for (int u = 0; u < GAF; ++u) {
                int idx = u * 256 + tid;
                int r = idx / (BK / 4), c4 = idx % (BK / 4);
                float vv[4] = {aF[u].x, aF[u].y, aF[u].z, aF[u].w};
                ushort4 hv, lv;
                unsigned short* hp = (unsigned short*)&hv;
                unsigned short* lp = (unsigned short*)&lv;
#pragma unroll
                for (int e = 0; e < 4; ++e) {
                    unsigned short hb = f2bf(vv[e]);
                    hp[e] = hb; lp[e] = f2bf(vv[e] - bfs2f(hb));
                }
                int off = (c4 / 8) * BM * 64 + r * 64 + (c4 & 7) * 8;
                *(ushort4*)(sAh + off) = hv;
                *(ushort4*)(sAl + off) = lv;
            }
        } else {
#pragma unroll
            for (int u = 0; u < GAP; ++u) {
                int idx = u * 256 + tid;
                int r = idx / (BK / 8), c8 = idx % (BK / 8);
                int off = (c8 / 4) * BM * 64 + r * 64 + (c8 & 3) * 16;
                *(int4*)(sAh + off) = aH[u];
                *(int4*)(sAl + off) = aL[u];
            }
        }
    };
    auto storeB = [&]() {
        if (BMODE == 0) {
#pragma unroll
            for (int u = 0; u < GBF; ++u) {
                int idx = u * 256 + tid;
                int r = idx / (BK / 4), c4 = idx % (BK / 4);
                float vv[4] = {bF[u].x, bF[u].y, bF[u].z, bF[u].w};
                ushort4 hv, lv;
                unsigned short* hp = (unsigned short*)&hv;
                unsigned short* lp = (unsigned short*)&lv;
#pragma unroll
                for (int e = 0; e < 4; ++e) {
                    unsigned short hb = f2bf(vv[e]);
                    hp[e] = hb; lp[e] = f2bf(vv[e] - bfs2f(hb));
                }
                int off = (c4 / 8) * BN * 64 + r * 64 + (c4 & 7) * 8;
                *(ushort4*)(sBh + off) = hv;
                *(ushort4*)(sBl + off) = lv;
            }
        } else {
#pragma unroll
            for (int u = 0; u < GBP; ++u) {
                int idx = u * 256 + tid;
                int r = idx / (BK / 8), c8 = idx % (BK / 8);
                int off = (c8 / 4) * BN * 64 + r * 64 + (c8 & 3) * 16;
                *(int4*)(sBh + off) = bH[u];
                *(int4*)(sBl + off) = bL[u];
            }
        }
    };

    loadA(kBase); loadB(kBase);
    for (int k0 = kBase; k0 < kEnd; k0 += BK) {
        storeA(); storeB();
        __syncthreads();
        if (k0 + BK < kEnd) { loadA(k0 + BK); loadB(k0 + BK); }  // prefetch
#pragma unroll
        for (int kb = 0; kb < KB; ++kb) {
            bf16x8 ah[FM], al[FM], bh[FN], bl[FN];
#pragma unroll
            for (int fm = 0; fm < FM; ++fm) {
                int off = kb * BM * 64 + (wm * (BM / 2) + fm * 16 + t16) * 64 + q * 16;
                ah[fm] = *(const bf16x8*)(sAh + off);
                al[fm] = *(const bf16x8*)(sAl + off);
            }
#pragma unroll
            for (int fn = 0; fn < FN; ++fn) {
                int off = kb * BN * 64 + (wn * (BN / 2) + fn * 16 + t16) * 64 + q * 16;
                bh[fn] = *(const bf16x8*)(sBh + off);
                bl[fn] = *(const bf16x8*)(sBl + off);
            }
#pragma unroll
            for (int fm = 0; fm < FM; ++fm)
#pragma unroll
                for (int fn = 0; fn < FN; ++fn) {
                    acc[fm][fn] = __builtin_amdgcn_mfma_f32_16x16x32_bf16(ah[fm], bh[fn], acc[fm][fn], 0, 0, 0);
                    acc[fm][fn] = __builtin_amdgcn_mfma_f32_16x16x32_bf16(al[fm], bh[fn], acc[fm][fn], 0, 0, 0);
                    acc[fm][fn] = __builtin_amdgcn_mfma_f32_16x16x32_bf16(ah[fm], bl[fn], acc[fm][fn], 0, 0, 0);
                }
        }
        __syncthreads();
    }

    // ---- epilogue: C/D layout col=lane&15, row=(lane>>4)*4+reg  (m89/m91)
#pragma unroll
    for (int fm = 0; fm < FM; ++fm) {
        int row0 = tileM + wm * (BM / 2) + fm * 16 + q * 4;
#pragma unroll
        for (int fn = 0; fn < FN; ++fn) {
            int col = tileN + wn * (BN / 2) + fn * 16 + t16;
            float* Cd = C; int cc2 = col;
            if (CSPLIT && col >= ldc) { Cd = C1; cc2 = col - ldc; }
            float bv = (EPI == 2) ? bias[col] : 0.f;
#pragma unroll
            for (int r = 0; r < 4; ++r) {
                float v = acc[fm][fn][r];
                if (EPI == 2) { v = fminf(v + bv, 60.f); v = log1pf(__expf(v)); }
                Cd[(size_t)(row0 + r) * ldc + cc2] = v;
            }
        }
    }
}

// ---------------------------------------------------------------------------
// reduce split-K partials (+bias) -> hi/lo planes (+ optional last-row fp32)
__global__ __launch_bounds__(256) void reduce_k(
    const float* __restrict__ part, int Z, int pstride, int n,
    const float* __restrict__ bias, int colmask,
    unsigned short* __restrict__ hi, unsigned short* __restrict__ lo,
    float* __restrict__ hlast, int colbits)
{
    int i = blockIdx.x * 256 + threadIdx.x;
    if (i >= n) return;
    float s = 0.f;
    for (int z = 0; z < Z; ++z) s += part[(size_t)z * pstride + i];
    if (bias) s += bias[i & colmask];
    unsigned short hb = f2bf(s);
    hi[i] = hb; lo[i] = f2bf(s - bfs2f(hb));
    if (hlast) {
        int row = i >> colbits;
        if ((row & 255) == 255)
            hlast[((row >> 8) << colbits) + (i & colmask)] = s;
    }
}

// causal depthwise conv (DC=4) + SiLU: xbuf(1024x1024) -> xc planes
__global__ __launch_bounds__(256) void conv_silu_k(
    const float* __restrict__ xb, const float* __restrict__ cw,
    const float* __restrict__ cb, unsigned short* __restrict__ xch,
    unsigned short* __restrict__ xcl)
{
    int i  = blockIdx.x * 256 + threadIdx.x;  // (bl, d)
    int d  = i & 1023;
    int bl = i >> 10;
    int l  = bl & 255;
    float a = cb[d];
#pragma unroll
    for (int k = 0; k < 4; ++k) {
        int ls = l + k - 3;
        if (ls >= 0) a += xb[(size_t)(bl + k - 3) * 1024 + d] * cw[d * 4 + k];
    }
    float v = a / (1.f + __expf(-a));
    unsigned short hb = f2bf(v);
    xch[i] = hb; xcl[i] = f2bf(v - bfs2f(hb));
}

// ---------------------------------------------------------------------------
// selective scan fused with +xc*D and *silu(z).
// LDS-staged: dt/xc/z/BmCm for a 64-step chunk are loaded coalesced into LDS,
// so the sequential recurrence touches only LDS + registers (the serial chain
// is one FMA per state per step; exp/c1/Cm are recurrence-independent).
// 8 threads per channel (2 states each); 128 blocks = 4 b x 32 chunks of 32 ch.
__global__ __launch_bounds__(256) void scan_k(
    const float* __restrict__ zb,
    const unsigned short* __restrict__ xch, const unsigned short* __restrict__ xcl,
    const unsigned short* __restrict__ xdh, const unsigned short* __restrict__ xdl,
    const float* __restrict__ dt, const float* __restrict__ Alog,
    const float* __restrict__ Dp,
    unsigned short* __restrict__ ygh, unsigned short* __restrict__ ygl)
{
    __shared__ float sdt[2048], sxc[2048], szz[2048], sbc[2048];  // 32 KB
    int b   = blockIdx.x >> 5;
    int d0  = (blockIdx.x & 31) << 5;
    int ch  = threadIdx.x >> 3;           // channel within chunk (0..31)
    int d   = d0 + ch;
    int sub = threadIdx.x & 7;
    int j0  = sub * 2;                    // this thread's first state idx
    float An[2], hst[2] = {0.f, 0.f};
    An[0] = -__expf(Alog[d * 16 + j0]);
    An[1] = -__expf(Alog[d * 16 + j0 + 1]);
    float Dd  = Dp[d];
    int   bl0 = b * 256;

    for (int c = 0; c < 4; ++c) {
        __syncthreads();
#pragma unroll
        for (int it = 0; it < 8; ++it) {
            int j2 = it * 256 + threadIdx.x;
            int ll = j2 >> 5, dd = j2 & 31;
            size_t row = (size_t)(bl0 + c * 64 + ll);
            size_t gi  = row * 1024 + d0 + dd;
            sdt[j2] = dt[gi];
            sxc[j2] = bfs2f(xch[gi]) + bfs2f(xcl[gi]);
            szz[j2] = zb[gi];
            size_t bi = row * 64 + 32 + dd;
            sbc[j2] = bfs2f(xdh[bi]) + bfs2f(xdl[bi]);
        }
        __syncthreads();
#pragma unroll 4
        for (int li = 0; li < 64; ++li) {
            float dtv = sdt[li * 32 + ch];
            float xcv = sxc[li * 32 + ch];
            float c1  = dtv * xcv;
            float dA0 = __expf(dtv * An[0]);
            float dA1 = __expf(dtv * An[1]);
            float B0  = sbc[li * 32 + j0],      B1 = sbc[li * 32 + j0 + 1];
            float C0  = sbc[li * 32 + 16 + j0], C1 = sbc[li * 32 + 16 + j0 + 1];
            hst[0] = dA0 * hst[0] + c1 * B0;
            hst[1] = dA1 * hst[1] + c1 * B1;
            float y = hst[0] * C0 + hst[1] * C1;
            y += __shfl_xor(y, 1);
            y += __shfl_xor(y, 2);
            y += __shfl_xor(y, 4);
            if (sub == 0) {
                float zv = szz[li * 32 + ch];
                float sg = zv / (1.f + __expf(-zv));
                float v  = (y + xcv * Dd) * sg;
                unsigned short hb = f2bf(v);
                size_t o = (size_t)(bl0 + c * 64 + li) * 1024 + d;
                ygh[o] = hb; ygl[o] = f2bf(v - bfs2f(hb));
            }
        }
    }
}

// ---------------------------------------------------------------------------
// LayerNorm of hlast (4 x 512) -> hn
__global__ __launch_bounds__(512) void ln_k(
    const float* __restrict__ hlast, const float* __restrict__ g,
    const float* __restrict__ bb, float* __restrict__ hn)
{
    __shared__ float red[16];
    int b = blockIdx.x, k = threadIdx.x;
    float x = hlast[b * 512 + k];
    float s = x, s2 = x * x;
#pragma unroll
    for (int m = 32; m; m >>= 1) { s += __shfl_xor(s, m, 64); s2 += __shfl_xor(s2, m, 64); }
    if ((k & 63) == 0) { red[k >> 6] = s; red[8 + (k >> 6)] = s2; }
    __syncthreads();
    float ts = 0.f, ts2 = 0.f;
#pragma unroll
    for (int j = 0; j < 8; ++j) { ts += red[j]; ts2 += red[8 + j]; }
    float mu   = ts * (1.f / 512.f);
    float var  = ts2 * (1.f / 512.f) - mu * mu;
    float rstd = rsqrtf(var + 1e-5f);
    hn[b * 512 + k] = (x - mu) * rstd * g[k] + bb[k];
}

// final: out(4,16384) = hn(4,512) @ out_w(16384,512)^T + out_b  (fp32)
__global__ __launch_bounds__(256) void final_k(
    const float* __restrict__ hn, const float* __restrict__ W,
    const float* __restrict__ ob, float* __restrict__ out)
{
    int wid = threadIdx.x >> 6, lane = threadIdx.x & 63;
    float a[4][8];
#pragma unroll
    for (int b2 = 0; b2 < 4; ++b2) {
        float4 v0 = *(const float4*)&hn[b2 * 512 + lane * 8];
        float4 v1 = *(const float4*)&hn[b2 * 512 + lane * 8 + 4];
        a[b2][0] = v0.x; a[b2][1] = v0.y; a[b2][2] = v0.z; a[b2][3] = v0.w;
        a[b2][4] = v1.x; a[b2][5] = v1.y; a[b2][6] = v1.z; a[b2][7] = v1.w;
    }
#pragma unroll 1
    for (int it = 0; it < 8; ++it) {
        int n = blockIdx.x * 4 + wid + it * 2048;
        const float* W32 = W + (size_t)n * 512 + lane * 8;
        float4 v0 = *(const float4*)W32;
        float4 v1 = *(const float4*)(W32 + 4);
        float wf[8] = {v0.x, v0.y, v0.z, v0.w, v1.x, v1.y, v1.z, v1.w};
        float s0 = 0.f, s1 = 0.f, s2 = 0.f, s3 = 0.f;
#pragma unroll
        for (int j = 0; j < 8; ++j) {
            s0 += a[0][j] * wf[j]; s1 += a[1][j] * wf[j];
            s2 += a[2][j] * wf[j]; s3 += a[3][j] * wf[j];
        }
#pragma unroll
        for (int m = 32; m; m >>= 1) {
            s0 += __shfl_xor(s0, m, 64); s1 += __shfl_xor(s1, m, 64);
            s2 += __shfl_xor(s2, m, 64); s3 += __shfl_xor(s3, m, 64);
        }
        if (lane == 0) {
            float bv = ob[n];
            out[0 * 16384 + n] = s0 + bv;
            out[1 * 16384 + n] = s1 + bv;
            out[2 * 16384 + n] = s2 + bv;
            out[3 * 16384 + n] = s3 + bv;
        }
    }
}

// ---------------------------------------------------------------------------
extern "C" void kernel_launch(void* const* d_in, const int* in_sizes, int n_in,
                              void* d_out, int out_size, void* d_ws, size_t ws_size,
                              hipStream_t stream)
{
    const float* x      = (const float*)d_in[0];
    const float* in_w   = (const float*)d_in[1];
    const float* in_b   = (const float*)d_in[2];
    const float* ln_g   = (const float*)d_in[3];
    const float* ln_b   = (const float*)d_in[4];
    const float* out_w  = (const float*)d_in[5];
    const float* out_b  = (const float*)d_in[6];
    const float* m_in_w = (const float*)d_in[7];
    const float* conv_w = (const float*)d_in[8];
    const float* conv_b = (const float*)d_in[9];
    const float* xproj_w= (const float*)d_in[10];
    const float* dt_w   = (const float*)d_in[11];
    const float* dt_b   = (const float*)d_in[12];
    const float* A_log  = (const float*)d_in[13];
    const float* D_p    = (const float*)d_in[14];
    const float* m_out_w= (const float*)d_in[15];

    // ---- ws layout, peak 19.3 MB (< proven-safe 23.3 MB) ----
    char* W = (char*)d_ws;
    unsigned short* hplh = (unsigned short*)(W + 0);          // h hi  1 MB
    unsigned short* hpll = (unsigned short*)(W + 1048576);    // h lo  1 MB
    float* hlast = (float*)(W + 2097152);                     // 8 KB
    float* hn    = (float*)(W + 2162688);                     // 8 KB
    float* xbuf  = (float*)(W + 2228224);                     // 4 MB
    float* zbuf  = (float*)(W + 6422528);                     // 4 MB
    unsigned short* xch = (unsigned short*)(W + 10616832);    // 2 MB
    unsigned short* xcl = (unsigned short*)(W + 12713984);    // 2 MB
    float* dtb   = (float*)(W + 14811136);                    // 4 MB
    unsigned short* xdbh  = (unsigned short*)(W + 19005440);  // 128 KB
    unsigned short* xdbl_ = (unsigned short*)(W + 19136512);  // 128 KB
    // aliases (sequencing-safe):
    float* part1 = (float*)(W + 2228224);                     // 16 MB, pre-layer only
    float* partx = (float*)(W + 14811136);                    // 2 MB, dead before dtb written
    float* parto = (float*)(W + 6422528);                     // 8 MB over zbuf+xc (dead post-scan)
    unsigned short* ygh = (unsigned short*)(W + 2228224);     // 2 MB over xbuf (dead post-conv)
    unsigned short* ygl = (unsigned short*)(W + 4325376);     // 2 MB

    // h = x @ in_w.T + in_b   (split-K=8, 1024 blocks = 4/CU)
    gemm_k<64,64,64,0,0,0,0><<<dim3(16,8,8),256,0,stream>>>(
        x, nullptr, in_w, nullptr, nullptr, part1, nullptr,
        16384, 16384, 512, 2048, 524288);
    reduce_k<<<2048,256,0,stream>>>(part1, 8, 524288, 524288, in_b, 511,
                                    hplh, hpll, hlast, 9);

    for (int i = 0; i < 4; ++i) {
        const float* iw = m_in_w  + (size_t)i * 1048576;
        const float* cw = conv_w  + (size_t)i * 4096;
        const float* cb = conv_b  + (size_t)i * 1024;
        const float* xw = xproj_w + (size_t)i * 65536;
        const float* dw = dt_w    + (size_t)i * 32768;
        const float* db = dt_b    + (size_t)i * 1024;
        const float* Al = A_log   + (size_t)i * 16384;
        const float* Dp = D_p     + (size_t)i * 1024;
        const float* ow = m_out_w + (size_t)i * 524288;

        // xz = h @ iw.T  (1024x2048, K=512) -> xbuf | zbuf  (256 blocks)
        gemm_k<64,128,64,1,0,0,1><<<dim3(16,16,1),256,0,stream>>>(
            hplh, hpll, iw, nullptr, nullptr, xbuf, zbuf, 512, 512, 1024, 512, 0);
        // xc = silu(causal_conv(xbuf)) -> planes
        conv_silu_k<<<4096,256,0,stream>>>(xbuf, cw, cb, xch, xcl);
        // xdbl = xc @ xw.T  (1024x64, K=1024, split-K=8 -> 128 blocks)
        gemm_k<64,64,64,1,0,0,0><<<dim3(16,1,8),256,0,stream>>>(
            xch, xcl, xw, nullptr, nullptr, partx, nullptr, 1024, 1024, 64, 128, 65536);
        reduce_k<<<256,256,0,stream>>>(partx, 8, 65536, 65536, nullptr, 63,
                                       xdbh, xdbl_, nullptr, 6);
        // dt = softplus(xdbl[:, :32] @ dw.T + db)  (1024x1024, K=32, 256 blocks)
        gemm_k<64,64,32,1,0,2,0><<<dim3(16,16,1),256,0,stream>>>(
            xdbh, xdbl_, dw, nullptr, db, dtb, nullptr, 64, 32, 1024, 32, 0);
        // yg = (scan + xc*D) * silu(z) -> planes (128 blocks, LDS-staged)
        scan_k<<<128,256,0,stream>>>(zbuf, xch, xcl, xdbh, xdbl_, dtb, Al, Dp,
                                     ygh, ygl);
        // h = yg @ ow.T  (1024x512, K=1024, split-K=4 -> 256 blocks)
        gemm_k<64,128,64,1,0,0,0><<<dim3(16,4,4),256,0,stream>>>(
            ygh, ygl, ow, nullptr, nullptr, parto, nullptr, 1024, 1024, 512, 256, 524288);
        reduce_k<<<2048,256,0,stream>>>(parto, 4, 524288, 524288, nullptr, 511,
                                        hplh, hpll, hlast, 9);
    }

    ln_k<<<4,512,0,stream>>>(hlast, ln_g, ln_b, hn);
    final_k<<<512,256,0,stream>>>(hn, out_w, out_b, (float*)d_out);
}